// Round 19
// baseline (165.635 us; speedup 1.0000x reference)
//
#include <hip/hip_runtime.h>
#include <hip/hip_bf16.h>

#define DEVINL static __device__ __forceinline__

typedef __attribute__((ext_vector_type(4))) float f32x4;
typedef __attribute__((ext_vector_type(8))) short bf16x8;

DEVINL short f2bf(float f) {
  __hip_bfloat16 h = __float2bfloat16(f);
  union { __hip_bfloat16 h; short s; } u; u.h = h; return u.s;
}
DEVINL float bf2f(short s) {
  union { unsigned u; float f; } v; v.u = ((unsigned)(unsigned short)s) << 16;
  return v.f;
}

// ---- prep: x f32->bf16 convert + ALL weight transposes in ONE launch ----
// id < 8192: cvt (4 f32->bf16 per thread from x).
// 8192 <= id < 9728: 24 batches of [2048][128] -> wall, 64x64 tiles (float4/short4).
// id >= 9728: wvec [2048][2048] -> wvecT, 64x64 tiles.
// LDS float[64][65]: stride-65 gives 2-lanes/bank on both phases (free).
__global__ void k_prep(const float* __restrict__ x, const float* __restrict__ wq,
                       const float* __restrict__ wkv, const float* __restrict__ wvec,
                       short* __restrict__ xbf, short* __restrict__ wall,
                       short* __restrict__ wvecT) {
  __shared__ float tile[64][65];
  const int id = blockIdx.x;
  if (id < 8192) {
    const int i = id * 256 + threadIdx.x;
    const float4 v = reinterpret_cast<const float4*>(x)[i];
    short4 o;
    o.x = f2bf(v.x); o.y = f2bf(v.y); o.z = f2bf(v.z); o.w = f2bf(v.w);
    reinterpret_cast<short4*>(xbf)[i] = o;
    return;
  }
  const float* ip;
  short* op;
  int C, r0, c0;
  if (id < 9728) {
    const int zid = id - 8192;
    const int z = zid >> 6, rem = zid & 63;  // batch, tile-in-batch
    c0 = (rem & 1) * 64;
    r0 = (rem >> 1) * 64;
    C = 128;
    if (z < 16)      ip = wq + (size_t)z * 262144;
    else if (z < 20) ip = wkv + (size_t)(z - 16) * 262144;
    else             ip = wkv + 1048576 + (size_t)(z - 20) * 262144;
    op = wall + (size_t)z * 262144;
  } else {
    const int rem = id - 9728;
    c0 = (rem & 31) * 64;
    r0 = (rem >> 5) * 64;
    C = 2048;
    ip = wvec;
    op = wvecT;
  }
  const int row = threadIdx.x >> 2, q = threadIdx.x & 3;
#pragma unroll
  for (int j = 0; j < 4; j++) {
    const int c = q * 16 + j * 4;
    const float4 v = *reinterpret_cast<const float4*>(ip + (size_t)(r0 + row) * C + c0 + c);
    tile[row][c] = v.x; tile[row][c + 1] = v.y; tile[row][c + 2] = v.z; tile[row][c + 3] = v.w;
  }
  __syncthreads();
#pragma unroll
  for (int j = 0; j < 4; j++) {
    const int c = q * 16 + j * 4;  // out-col chunk (= source row offset)
    short4 v;
    v.x = f2bf(tile[c][row]);
    v.y = f2bf(tile[c + 1][row]);
    v.z = f2bf(tile[c + 2][row]);
    v.w = f2bf(tile[c + 3][row]);
    *reinterpret_cast<short4*>(op + (size_t)(c0 + row) * 2048 + r0 + c) = v;
  }
}

// =================== BMxBNxK 4-phase MFMA GEMM (T2+T3+T4+T5+T1) ===================
// NOTE (r9-r13): frame-bound at ~845 TF; five structural variants measured null.
// mode 0 epilogue: q/k fused-RoPE scatter; V written TRANSPOSED direct to vT.

#define GBAR __builtin_amdgcn_s_barrier()
#define LGK asm volatile("s_waitcnt lgkmcnt(0)")
#define PR1 __builtin_amdgcn_s_setprio(1)
#define PR0 __builtin_amdgcn_s_setprio(0)
#define VMW { if constexpr (LPA + LPB == 4) asm volatile("s_waitcnt vmcnt(4)");       \
              else if constexpr (LPA + LPB == 3) asm volatile("s_waitcnt vmcnt(3)");  \
              else asm volatile("s_waitcnt vmcnt(2)"); }

template <int LN>
DEVINL void stage(char* dst, const short* src, int K, int tid) {
#pragma unroll
  for (int L = 0; L < LN; L++) {
    const int loc = L * 8192 + tid * 16;
    const int row = loc >> 7;
    const int gsw = ((loc >> 4) & 7) ^ (row & 7);
    __builtin_amdgcn_global_load_lds(
        (const __attribute__((address_space(1))) void*)(src + (size_t)row * K + gsw * 8),
        (__attribute__((address_space(3))) void*)(dst + loc), 16, 0, 0);
  }
}

#define SA(BUF, HALF, KT) \
  stage<LPA>((BUF) + (HALF) * (ABY / 2), Am + (size_t)((HALF) * (BM / 2)) * K + (KT) * 64, K, tid)
#define SB(BUF, HALF, KT) \
  stage<LPB>((BUF) + (HALF) * (BBY / 2), Bn + (size_t)((HALF) * (BN / 2)) * K + (KT) * 64, K, tid)

#define RDA(BUF, IH)                                                                   \
  { _Pragma("unroll")                                                                  \
    for (int kf_ = 0; kf_ < KFN; kf_++) {                                              \
      _Pragma("unroll")                                                                \
      for (int kk_ = 0; kk_ < 2; kk_++) {                                              \
        const int row_ = ((IH) * KFN + kf_) * 32 + wr * 16 + lr;                       \
        a[kf_ * 2 + kk_] = *(const bf16x8*)((BUF) + row_ * 128 +                       \
                                            (((kk_ * 4 + lu) ^ (lr & 7)) << 4));       \
      } } }

#define RDB(BUF, JH, ARR)                                                              \
  { _Pragma("unroll")                                                                  \
    for (int jf_ = 0; jf_ < JFN; jf_++) {                                              \
      _Pragma("unroll")                                                                \
      for (int kk_ = 0; kk_ < 2; kk_++) {                                              \
        const int row_ = ((JH) * JFN + jf_) * 64 + wc * 16 + lr;                       \
        ARR[jf_ * 2 + kk_] = *(const bf16x8*)((BUF) + row_ * 128 +                     \
                                              (((kk_ * 4 + lu) ^ (lr & 7)) << 4));     \
      } } }

#define MF(IH, JH, ARR)                                                                \
  { _Pragma("unroll")                                                                  \
    for (int kf_ = 0; kf_ < KFN; kf_++)                                                \
      { _Pragma("unroll")                                                              \
        for (int jf_ = 0; jf_ < JFN; jf_++)                                            \
          { _Pragma("unroll")                                                          \
            for (int kk_ = 0; kk_ < 2; kk_++)                                          \
              acc[(IH) * KFN + kf_][(JH) * JFN + jf_] =                                \
                  __builtin_amdgcn_mfma_f32_16x16x32_bf16(                             \
                      a[kf_ * 2 + kk_], ARR[jf_ * 2 + kk_],                            \
                      acc[(IH) * KFN + kf_][(JH) * JFN + jf_], 0, 0, 0);               \
          } } }

template <int BM, int BN>
__global__ __launch_bounds__(512, 2) void k_gemm256(
    const short* __restrict__ A, const short* __restrict__ Bt,
    void* __restrict__ Out0, void* __restrict__ Out1, void* __restrict__ Out2,
    int N, int K, int mode) {
  constexpr int LPA = BM / 128;
  constexpr int LPB = BN / 128;
  constexpr int KFN = BM / 64;
  constexpr int JFN = BN / 128;
  constexpr int ABY = BM * 128;
  constexpr int BBY = BN * 128;
  extern __shared__ __align__(16) char sm[];
  char* A0 = sm;
  char* A1 = sm + ABY;
  char* B0 = sm + 2 * ABY;
  char* B1 = sm + 2 * ABY + BBY;
  const int lin = blockIdx.x + gridDim.x * blockIdx.y;
  const int nc = N / BN;
  const int m0 = (lin / nc) * BM, n0 = (lin % nc) * BN;
  const int tid = threadIdx.x, lane = tid & 63, w = tid >> 6;
  const int wr = w & 1, wc = w >> 1;
  const int lr = lane & 15, lu = lane >> 4;
  const short* Am = A + (size_t)m0 * K;
  const short* Bn = Bt + (size_t)n0 * K;
  f32x4 acc[KFN * 2][JFN * 2] = {};
  bf16x8 a[KFN * 2], bJ0[JFN * 2], bJ1[JFN * 2];
  const int NIT = K >> 7;
  const int TMAX = (K >> 6) - 1;

  SA(A0, 0, 0); SB(B0, 1, 0); SA(A0, 1, 0); SB(B0, 0, 0);
  SA(A1, 0, 1); SB(B1, 1, 1);
  VMW; GBAR;

  for (int it = 0; it < NIT; ++it) {
    const int t1 = 2 * it + 1;
    const int t2 = (2 * it + 2 < TMAX) ? 2 * it + 2 : TMAX;
    const int t3 = (2 * it + 3 < TMAX) ? 2 * it + 3 : TMAX;
    RDA(A0, 0); RDB(B0, 0, bJ0); RDB(B0, 1, bJ1); SA(A1, 1, t1); SB(B1, 0, t1);
    GBAR; LGK; PR1; MF(0, 0, bJ0); MF(0, 1, bJ1); PR0; GBAR;
    RDA(A0, 1); SA(A0, 0, t2); SB(B0, 1, t2);
    GBAR; LGK; PR1; MF(1, 1, bJ1); MF(1, 0, bJ0); PR0; VMW; GBAR;
    RDA(A1, 0); RDB(B1, 0, bJ0); RDB(B1, 1, bJ1); SA(A0, 1, t2); SB(B0, 0, t2);
    GBAR; LGK; PR1; MF(0, 0, bJ0); MF(0, 1, bJ1); PR0; GBAR;
    RDA(A1, 1); SA(A1, 0, t3); SB(B1, 1, t3);
    GBAR; LGK; PR1; MF(1, 1, bJ1); MF(1, 0, bJ0); PR0; VMW; GBAR;
  }

  if (mode == 2) {
#pragma unroll
    for (int k = 0; k < KFN * 2; k++)
#pragma unroll
      for (int j = 0; j < JFN * 2; j++)
#pragma unroll
        for (int r = 0; r < 4; r++) {
          const int m = m0 + k * 32 + wr * 16 + lu * 4 + r;
          const int n = n0 + j * 64 + wc * 16 + lr;
          ((float*)Out0)[(size_t)m * N + n] = acc[k][j][r];
        }
  } else {
    const int i_rope = wc * 16 + lr;
    const float inv = __expf(-(float)i_rope * (float)(9.210340371976184 / 64.0));
    const bool has_qk = (n0 < 2560);
#pragma unroll
    for (int k = 0; k < KFN * 2; k++) {
      const int m_base = m0 + k * 32 + wr * 16 + lu * 4;
      const int bb = m_base >> 11, t0 = m_base & 2047;
      float sn[4], cs[4];
      if (has_qk) {
#pragma unroll
        for (int r = 0; r < 4; r++)
          sincosf((float)(t0 + r) * inv, &sn[r], &cs[r]);
      }
#pragma unroll
      for (int u = 0; u < JFN; u++) {
        const int n_lo = n0 + (2 * u) * 64 + wc * 16 + lr;
        const int reg = (n_lo < 2048) ? 0 : ((n_lo < 2560) ? 1 : 2);
        if (reg == 2) {
#pragma unroll
          for (int p = 0; p < 2; p++) {
            const int nn = n_lo + p * 64 - 2560;
            short4 v4;
            v4.x = f2bf(acc[k][2 * u + p][0]);
            v4.y = f2bf(acc[k][2 * u + p][1]);
            v4.z = f2bf(acc[k][2 * u + p][2]);
            v4.w = f2bf(acc[k][2 * u + p][3]);
            *reinterpret_cast<short4*>((short*)Out2 + (((size_t)(bb * 4 + (nn >> 7))) << 18) +
                                       (size_t)(nn & 127) * 2048 + t0) = v4;
          }
        } else {
#pragma unroll
          for (int r = 0; r < 4; r++) {
            const int t = t0 + r;
            float lo = acc[k][2 * u][r], hi = acc[k][2 * u + 1][r];
            const float l2 = lo * cs[r] - hi * sn[r];
            const float h2 = hi * cs[r] + lo * sn[r];
            const float sc = (reg == 0) ? 0.08838834764831845f : 1.0f;
            lo = l2 * sc; hi = h2 * sc;
#pragma unroll
            for (int p = 0; p < 2; p++) {
              const int n = n_lo + p * 64;
              const float v = p ? hi : lo;
              if (n < 2048) {
                ((short*)Out0)[(((size_t)(bb * 16 + (n >> 7))) << 18) + t * 128 + (n & 127)] =
                    f2bf(v);
              } else {
                const int nn = n - 2048;
                ((short*)Out1)[(((size_t)(bb * 4 + (nn >> 7))) << 18) + t * 128 + (nn & 127)] =
                    f2bf(v);
              }
            }
          }
        }
      }
    }
  }
}

// ---------------- flash attention, sliding window + tanh soft-cap ----------------
// QBLK=128 (r16-proven): 512 thr, 8 waves x 16 t-rows; single-buffered K/V
// (r17 A/B: double-buffer+vmcnt(4) cost more via occupancy 3->2 than it hid).
__global__ __launch_bounds__(512) void k_attn(
    const short* __restrict__ q, const short* __restrict__ kk,
    const short* __restrict__ vT, short* __restrict__ enc) {
  __shared__ __align__(16) short lK[64 * 128];   // [s][h], byte ^= ((s&7)<<4)
  __shared__ __align__(16) short lV[128 * 64];   // [h][s], byte ^= ((h&7)<<4)
  __shared__ __align__(16) short lP[8][16 * 64]; // per-wave P [t][s], ^((t&7)<<4)
  const int bn = blockIdx.x, b = bn >> 4, n = bn & 15, kv = n >> 2;
  const int qt0 = (15 - blockIdx.y) * 128;  // heavy blocks dispatched first
  const int tid = threadIdx.x, lane = tid & 63, w = tid >> 6;
  const int lr = lane & 15, lu = lane >> 4;
  const short* qbase = q + (((size_t)(b * 16 + n)) << 18) + (size_t)(qt0 + w * 16) * 128;
  bf16x8 qa[4];
#pragma unroll
  for (int c = 0; c < 4; c++)
    qa[c] = *reinterpret_cast<const bf16x8*>(qbase + lr * 128 + c * 32 + lu * 8);
  f32x4 o[8] = {};
  float lsum = 0.f;
  const short* kbase = kk + (((size_t)(b * 4 + kv)) << 18);
  const short* vbase = vT + (((size_t)(b * 4 + kv)) << 18);
  char* lPw = (char*)lP[w];
  const int tw = qt0 + w * 16;
  const int t_row = tw + lu * 4;
  int st0 = qt0 - 1023; if (st0 < 0) st0 = 0;
  st0 >>= 6;
  const int stE = (qt0 + 127) >> 6;
  for (int st = st0; st <= stE; st++) {
    const int s0 = st << 6;
#pragma unroll
    for (int c = 0; c < 2; c++) {
      const int L = c * 8192 + tid * 16;
      {  // K tile: linear LDS dest, pre-swizzled global source
        const int s = L >> 8, slot = (L >> 4) & 15;
        const int sp = slot ^ (s & 7);
        __builtin_amdgcn_global_load_lds(
            (const __attribute__((address_space(1))) void*)(kbase + (size_t)(s0 + s) * 128 + sp * 8),
            (__attribute__((address_space(3))) void*)((char*)lK + L), 16, 0, 0);
      }
      {  // V tile
        const int h = L >> 7, slot = (L >> 4) & 7;
        const int u = slot ^ (h & 7);
        __builtin_amdgcn_global_load_lds(
            (const __attribute__((address_space(1))) void*)(vbase + (size_t)h * 2048 + s0 + u * 8),
            (__attribute__((address_space(3))) void*)((char*)lV + L), 16, 0, 0);
      }
    }
    __syncthreads();
    // ---- QK^T (swapped) ----
    f32x4 sc[4];
    __builtin_amdgcn_s_setprio(1);
#pragma unroll
    for (int cg = 0; cg < 4; cg++) {
      sc[cg] = (f32x4){0.f, 0.f, 0.f, 0.f};
      const int s = cg * 16 + lr;
      const int sw = (s & 7) << 4;
#pragma unroll
      for (int c = 0; c < 4; c++) {
        bf16x8 kb = *reinterpret_cast<const bf16x8*>((char*)lK + s * 256 + (((c * 4 + lu) << 4) ^ sw));
        sc[cg] = __builtin_amdgcn_mfma_f32_16x16x32_bf16(kb, qa[c], sc[cg], 0, 0, 0);
      }
    }
    __builtin_amdgcn_s_setprio(0);
    // ---- cubic soft-cap + exp, pack pairs, write P (b32) ----
    const bool allv = (s0 + 63 <= tw) && (s0 + 1008 >= tw);
    if (allv) {
#pragma unroll
      for (int cg = 0; cg < 4; cg++) {
        float pr[4];
#pragma unroll
        for (int r = 0; r < 4; r++) {
          const float x = sc[cg][r];
          const float cap = __builtin_fmaf(x * x * x, -1.3333333e-4f, x);
          const float p = __expf(cap);
          lsum += p;
          pr[r] = p;
        }
        unsigned w0, w1;
        asm("v_cvt_pk_bf16_f32 %0, %1, %2" : "=v"(w0) : "v"(pr[0]), "v"(pr[1]));
        asm("v_cvt_pk_bf16_f32 %0, %1, %2" : "=v"(w1) : "v"(pr[2]), "v"(pr[3]));
        const int sb = (cg * 16 + lu * 4) << 1;
        *(unsigned*)(lPw + (lr << 7) + (sb ^ ((lr & 7) << 4))) = w0;
        *(unsigned*)(lPw + (lr << 7) + ((sb + 4) ^ ((lr & 7) << 4))) = w1;
      }
    } else {
      const int t = tw + lr;
#pragma unroll
      for (int cg = 0; cg < 4; cg++) {
        float pr[4];
#pragma unroll
        for (int r = 0; r < 4; r++) {
          const int s = s0 + cg * 16 + lu * 4 + r;
          const bool valid = (s <= t) & (s + 1024 > t);
          const float x = sc[cg][r];
          const float cap = __builtin_fmaf(x * x * x, -1.3333333e-4f, x);
          float p = __expf(cap);
          p = valid ? p : 0.f;
          lsum += p;
          pr[r] = p;
        }
        unsigned w0, w1;
        asm("v_cvt_pk_bf16_f32 %0, %1, %2" : "=v"(w0) : "v"(pr[0]), "v"(pr[1]));
        asm("v_cvt_pk_bf16_f32 %0, %1, %2" : "=v"(w1) : "v"(pr[2]), "v"(pr[3]));
        const int sb = (cg * 16 + lu * 4) << 1;
        *(unsigned*)(lPw + (lr << 7) + (sb ^ ((lr & 7) << 4))) = w0;
        *(unsigned*)(lPw + (lr << 7) + ((sb + 4) ^ ((lr & 7) << 4))) = w1;
      }
    }
    // ---- PV ----
#pragma unroll
    for (int ks = 0; ks < 2; ks++) {
      const bf16x8 pf = *reinterpret_cast<const bf16x8*>(
          lPw + (lr << 7) + ((ks * 64 + lu * 16) ^ ((lr & 7) << 4)));
      __builtin_amdgcn_s_setprio(1);
#pragma unroll
      for (int oc = 0; oc < 8; oc++) {
        const int h = oc * 16 + lr;
        bf16x8 vb = *reinterpret_cast<const bf16x8*>(
            (char*)lV + h * 128 + (((ks * 4 + lu) << 4) ^ ((h & 7) << 4)));
        o[oc] = __builtin_amdgcn_mfma_f32_16x16x32_bf16(pf, vb, o[oc], 0, 0, 0);
      }
      __builtin_amdgcn_s_setprio(0);
    }
    __syncthreads();
  }
  // ---- reduce: lane holds partial sum for column t=tw+lr ----
  float tot = lsum;
  tot += __shfl_xor(tot, 16, 64);
  tot += __shfl_xor(tot, 32, 64);
  float rs[4];
#pragma unroll
  for (int r = 0; r < 4; r++)
    rs[r] = 1.f / __shfl(tot, lu * 4 + r, 64);
#pragma unroll
  for (int oc = 0; oc < 8; oc++)
#pragma unroll
    for (int r = 0; r < 4; r++) {
      const int t = t_row + r;
      enc[((size_t)b * 2048 + t) * 2048 + n * 128 + oc * 16 + lr] = f2bf(o[oc][r] * rs[r]);
    }
}

extern "C" void kernel_launch(void* const* d_in, const int* in_sizes, int n_in,
                              void* d_out, int out_size, void* d_ws, size_t ws_size,
                              hipStream_t stream) {
  (void)in_sizes; (void)n_in; (void)out_size; (void)ws_size;
  const float* x    = (const float*)d_in[0];
  const float* wq   = (const float*)d_in[3];
  const float* wkv  = (const float*)d_in[4];
  const float* wvec = (const float*)d_in[5];
  char* ws = (char*)d_ws;
  size_t off = 0;
  short* xbf   = (short*)(ws + off); off += (size_t)8388608 * 2;            // x bf16 [B*T][D]
  short* wall  = (short*)(ws + off); off += (size_t)3072 * 2048 * 2;        // [wqT|wkT|wvT] rows x K
  short* wvecT = (short*)(ws + off); off += (size_t)2048 * 2048 * 2;        // [d][nh]
  short* qbuf  = (short*)(ws + off); off += (size_t)2 * 16 * 2048 * 128 * 2; // q bf16 [b][n][t][h]
  short* kbuf  = (short*)(ws + off); off += (size_t)2 * 4 * 2048 * 128 * 2;  // k bf16 [b][kv][t][h]
  short* vTbuf = (short*)(ws + off); off += (size_t)2 * 4 * 128 * 2048 * 2;  // v^T [b][kv][h][s]
  short* encb  = (short*)(ws + off); off += (size_t)2 * 2048 * 2048 * 2;     // [b][t][nh]

  hipFuncSetAttribute(reinterpret_cast<const void*>(&k_gemm256<128, 384>),
                      hipFuncAttributeMaxDynamicSharedMemorySize, 131072);
  hipFuncSetAttribute(reinterpret_cast<const void*>(&k_gemm256<128, 256>),
                      hipFuncAttributeMaxDynamicSharedMemorySize, 98304);

  k_prep<<<10752, 256, 0, stream>>>(x, wq, wkv, wvec, xbf, wall, wvecT);
  k_gemm256<128, 384><<<dim3(32, 8), 512, 131072, stream>>>(xbf, wall, qbuf, kbuf, vTbuf,
                                                            3072, 2048, 0);
  k_attn<<<dim3(32, 16), 512, 0, stream>>>(qbuf, kbuf, vTbuf, encb);
  k_gemm256<128, 256><<<dim3(32, 8), 512, 98304, stream>>>(encb, wvecT, d_out, nullptr, nullptr,
                                                           2048, 2048, 2);
}

// Round 20
// 161.583 us; speedup vs baseline: 1.0251x; 1.0251x over previous
//
#include <hip/hip_runtime.h>
#include <hip/hip_bf16.h>

#define DEVINL static __device__ __forceinline__

typedef __attribute__((ext_vector_type(4))) float f32x4;
typedef __attribute__((ext_vector_type(8))) short bf16x8;

DEVINL short f2bf(float f) {
  __hip_bfloat16 h = __float2bfloat16(f);
  union { __hip_bfloat16 h; short s; } u; u.h = h; return u.s;
}
DEVINL float bf2f(short s) {
  union { unsigned u; float f; } v; v.u = ((unsigned)(unsigned short)s) << 16;
  return v.f;
}

// ---- prep: x f32->bf16 convert + ALL weight transposes in ONE launch ----
// (r18 lesson: the 64x64 float4/short4 rewrite regressed — this scalar-tile
// version is HBM/latency-bound, not store-width-bound. Keep it.)
__global__ void k_prep(const float* __restrict__ x, const float* __restrict__ wq,
                       const float* __restrict__ wkv, const float* __restrict__ wvec,
                       short* __restrict__ xbf, short* __restrict__ wall,
                       short* __restrict__ wvecT) {
  __shared__ float tile[32][33];
  const int id = blockIdx.x;
  if (id < 8192) {
    const int i = id * 256 + threadIdx.x;
    const float4 v = reinterpret_cast<const float4*>(x)[i];
    short4 o;
    o.x = f2bf(v.x); o.y = f2bf(v.y); o.z = f2bf(v.z); o.w = f2bf(v.w);
    reinterpret_cast<short4*>(xbf)[i] = o;
    return;
  }
  const float* ip;
  short* op;
  int C, r0, c0;
  if (id < 14336) {
    const int zid = id - 8192;
    const int z = zid >> 8, rem = zid & 255;
    c0 = (rem & 3) * 32;
    r0 = (rem >> 2) * 32;
    C = 128;
    if (z < 16)      ip = wq + (size_t)z * 262144;
    else if (z < 20) ip = wkv + (size_t)(z - 16) * 262144;
    else             ip = wkv + 1048576 + (size_t)(z - 20) * 262144;
    op = wall + (size_t)z * 262144;
  } else {
    const int rem = id - 14336;
    c0 = (rem & 63) * 32;
    r0 = (rem >> 6) * 32;
    C = 2048;
    ip = wvec;
    op = wvecT;
  }
  const int tx = threadIdx.x & 31, ty = threadIdx.x >> 5;
#pragma unroll
  for (int k = 0; k < 4; k++)
    tile[ty + k * 8][tx] = ip[(size_t)(r0 + ty + k * 8) * C + c0 + tx];
  __syncthreads();
#pragma unroll
  for (int k = 0; k < 4; k++)
    op[(size_t)(c0 + ty + k * 8) * 2048 + r0 + tx] = f2bf(tile[tx][ty + k * 8]);
}

// =================== BMxBNxK 4-phase MFMA GEMM (T2+T3+T4+T5+T1) ===================
// NOTE (r9-r13): frame-bound at ~845 TF; five structural variants measured null.
// mode 0 epilogue: q/k fused-RoPE scatter; V written TRANSPOSED direct to vT.

#define GBAR __builtin_amdgcn_s_barrier()
#define LGK asm volatile("s_waitcnt lgkmcnt(0)")
#define PR1 __builtin_amdgcn_s_setprio(1)
#define PR0 __builtin_amdgcn_s_setprio(0)
#define VMW { if constexpr (LPA + LPB == 4) asm volatile("s_waitcnt vmcnt(4)");       \
              else if constexpr (LPA + LPB == 3) asm volatile("s_waitcnt vmcnt(3)");  \
              else asm volatile("s_waitcnt vmcnt(2)"); }

template <int LN>
DEVINL void stage(char* dst, const short* src, int K, int tid) {
#pragma unroll
  for (int L = 0; L < LN; L++) {
    const int loc = L * 8192 + tid * 16;
    const int row = loc >> 7;
    const int gsw = ((loc >> 4) & 7) ^ (row & 7);
    __builtin_amdgcn_global_load_lds(
        (const __attribute__((address_space(1))) void*)(src + (size_t)row * K + gsw * 8),
        (__attribute__((address_space(3))) void*)(dst + loc), 16, 0, 0);
  }
}

#define SA(BUF, HALF, KT) \
  stage<LPA>((BUF) + (HALF) * (ABY / 2), Am + (size_t)((HALF) * (BM / 2)) * K + (KT) * 64, K, tid)
#define SB(BUF, HALF, KT) \
  stage<LPB>((BUF) + (HALF) * (BBY / 2), Bn + (size_t)((HALF) * (BN / 2)) * K + (KT) * 64, K, tid)

#define RDA(BUF, IH)                                                                   \
  { _Pragma("unroll")                                                                  \
    for (int kf_ = 0; kf_ < KFN; kf_++) {                                              \
      _Pragma("unroll")                                                                \
      for (int kk_ = 0; kk_ < 2; kk_++) {                                              \
        const int row_ = ((IH) * KFN + kf_) * 32 + wr * 16 + lr;                       \
        a[kf_ * 2 + kk_] = *(const bf16x8*)((BUF) + row_ * 128 +                       \
                                            (((kk_ * 4 + lu) ^ (lr & 7)) << 4));       \
      } } }

#define RDB(BUF, JH, ARR)                                                              \
  { _Pragma("unroll")                                                                  \
    for (int jf_ = 0; jf_ < JFN; jf_++) {                                              \
      _Pragma("unroll")                                                                \
      for (int kk_ = 0; kk_ < 2; kk_++) {                                              \
        const int row_ = ((JH) * JFN + jf_) * 64 + wc * 16 + lr;                       \
        ARR[jf_ * 2 + kk_] = *(const bf16x8*)((BUF) + row_ * 128 +                     \
                                              (((kk_ * 4 + lu) ^ (lr & 7)) << 4));     \
      } } }

#define MF(IH, JH, ARR)                                                                \
  { _Pragma("unroll")                                                                  \
    for (int kf_ = 0; kf_ < KFN; kf_++)                                                \
      { _Pragma("unroll")                                                              \
        for (int jf_ = 0; jf_ < JFN; jf_++)                                            \
          { _Pragma("unroll")                                                          \
            for (int kk_ = 0; kk_ < 2; kk_++)                                          \
              acc[(IH) * KFN + kf_][(JH) * JFN + jf_] =                                \
                  __builtin_amdgcn_mfma_f32_16x16x32_bf16(                             \
                      a[kf_ * 2 + kk_], ARR[jf_ * 2 + kk_],                            \
                      acc[(IH) * KFN + kf_][(JH) * JFN + jf_], 0, 0, 0);               \
          } } }

template <int BM, int BN>
__global__ __launch_bounds__(512, 2) void k_gemm256(
    const short* __restrict__ A, const short* __restrict__ Bt,
    void* __restrict__ Out0, void* __restrict__ Out1, void* __restrict__ Out2,
    int N, int K, int mode) {
  constexpr int LPA = BM / 128;
  constexpr int LPB = BN / 128;
  constexpr int KFN = BM / 64;
  constexpr int JFN = BN / 128;
  constexpr int ABY = BM * 128;
  constexpr int BBY = BN * 128;
  extern __shared__ __align__(16) char sm[];
  char* A0 = sm;
  char* A1 = sm + ABY;
  char* B0 = sm + 2 * ABY;
  char* B1 = sm + 2 * ABY + BBY;
  const int lin = blockIdx.x + gridDim.x * blockIdx.y;
  const int nc = N / BN;
  const int m0 = (lin / nc) * BM, n0 = (lin % nc) * BN;
  const int tid = threadIdx.x, lane = tid & 63, w = tid >> 6;
  const int wr = w & 1, wc = w >> 1;
  const int lr = lane & 15, lu = lane >> 4;
  const short* Am = A + (size_t)m0 * K;
  const short* Bn = Bt + (size_t)n0 * K;
  f32x4 acc[KFN * 2][JFN * 2] = {};
  bf16x8 a[KFN * 2], bJ0[JFN * 2], bJ1[JFN * 2];
  const int NIT = K >> 7;
  const int TMAX = (K >> 6) - 1;

  SA(A0, 0, 0); SB(B0, 1, 0); SA(A0, 1, 0); SB(B0, 0, 0);
  SA(A1, 0, 1); SB(B1, 1, 1);
  VMW; GBAR;

  for (int it = 0; it < NIT; ++it) {
    const int t1 = 2 * it + 1;
    const int t2 = (2 * it + 2 < TMAX) ? 2 * it + 2 : TMAX;
    const int t3 = (2 * it + 3 < TMAX) ? 2 * it + 3 : TMAX;
    RDA(A0, 0); RDB(B0, 0, bJ0); RDB(B0, 1, bJ1); SA(A1, 1, t1); SB(B1, 0, t1);
    GBAR; LGK; PR1; MF(0, 0, bJ0); MF(0, 1, bJ1); PR0; GBAR;
    RDA(A0, 1); SA(A0, 0, t2); SB(B0, 1, t2);
    GBAR; LGK; PR1; MF(1, 1, bJ1); MF(1, 0, bJ0); PR0; VMW; GBAR;
    RDA(A1, 0); RDB(B1, 0, bJ0); RDB(B1, 1, bJ1); SA(A0, 1, t2); SB(B0, 0, t2);
    GBAR; LGK; PR1; MF(0, 0, bJ0); MF(0, 1, bJ1); PR0; GBAR;
    RDA(A1, 1); SA(A1, 0, t3); SB(B1, 1, t3);
    GBAR; LGK; PR1; MF(1, 1, bJ1); MF(1, 0, bJ0); PR0; VMW; GBAR;
  }

  if (mode == 2) {
#pragma unroll
    for (int k = 0; k < KFN * 2; k++)
#pragma unroll
      for (int j = 0; j < JFN * 2; j++)
#pragma unroll
        for (int r = 0; r < 4; r++) {
          const int m = m0 + k * 32 + wr * 16 + lu * 4 + r;
          const int n = n0 + j * 64 + wc * 16 + lr;
          ((float*)Out0)[(size_t)m * N + n] = acc[k][j][r];
        }
  } else {
    const int i_rope = wc * 16 + lr;
    const float inv = __expf(-(float)i_rope * (float)(9.210340371976184 / 64.0));
    const bool has_qk = (n0 < 2560);
#pragma unroll
    for (int k = 0; k < KFN * 2; k++) {
      const int m_base = m0 + k * 32 + wr * 16 + lu * 4;
      const int bb = m_base >> 11, t0 = m_base & 2047;
      float sn[4], cs[4];
      if (has_qk) {
#pragma unroll
        for (int r = 0; r < 4; r++)
          sincosf((float)(t0 + r) * inv, &sn[r], &cs[r]);
      }
#pragma unroll
      for (int u = 0; u < JFN; u++) {
        const int n_lo = n0 + (2 * u) * 64 + wc * 16 + lr;
        const int reg = (n_lo < 2048) ? 0 : ((n_lo < 2560) ? 1 : 2);
        if (reg == 2) {
#pragma unroll
          for (int p = 0; p < 2; p++) {
            const int nn = n_lo + p * 64 - 2560;
            short4 v4;
            v4.x = f2bf(acc[k][2 * u + p][0]);
            v4.y = f2bf(acc[k][2 * u + p][1]);
            v4.z = f2bf(acc[k][2 * u + p][2]);
            v4.w = f2bf(acc[k][2 * u + p][3]);
            *reinterpret_cast<short4*>((short*)Out2 + (((size_t)(bb * 4 + (nn >> 7))) << 18) +
                                       (size_t)(nn & 127) * 2048 + t0) = v4;
          }
        } else {
#pragma unroll
          for (int r = 0; r < 4; r++) {
            const int t = t0 + r;
            float lo = acc[k][2 * u][r], hi = acc[k][2 * u + 1][r];
            const float l2 = lo * cs[r] - hi * sn[r];
            const float h2 = hi * cs[r] + lo * sn[r];
            const float sc = (reg == 0) ? 0.08838834764831845f : 1.0f;
            lo = l2 * sc; hi = h2 * sc;
#pragma unroll
            for (int p = 0; p < 2; p++) {
              const int n = n_lo + p * 64;
              const float v = p ? hi : lo;
              if (n < 2048) {
                ((short*)Out0)[(((size_t)(bb * 16 + (n >> 7))) << 18) + t * 128 + (n & 127)] =
                    f2bf(v);
              } else {
                const int nn = n - 2048;
                ((short*)Out1)[(((size_t)(bb * 4 + (nn >> 7))) << 18) + t * 128 + (nn & 127)] =
                    f2bf(v);
              }
            }
          }
        }
      }
    }
  }
}

// ---------------- flash attention, sliding window + tanh soft-cap ----------------
// QBLK=128 (r16-proven): 512 thr, 8 waves x 16 t-rows; single-buffered K/V
// (r17 A/B: double-buffer+vmcnt(4) cost more via occupancy 3->2 than it hid).
__global__ __launch_bounds__(512) void k_attn(
    const short* __restrict__ q, const short* __restrict__ kk,
    const short* __restrict__ vT, short* __restrict__ enc) {
  __shared__ __align__(16) short lK[64 * 128];   // [s][h], byte ^= ((s&7)<<4)
  __shared__ __align__(16) short lV[128 * 64];   // [h][s], byte ^= ((h&7)<<4)
  __shared__ __align__(16) short lP[8][16 * 64]; // per-wave P [t][s], ^((t&7)<<4)
  const int bn = blockIdx.x, b = bn >> 4, n = bn & 15, kv = n >> 2;
  const int qt0 = (15 - blockIdx.y) * 128;  // heavy blocks dispatched first
  const int tid = threadIdx.x, lane = tid & 63, w = tid >> 6;
  const int lr = lane & 15, lu = lane >> 4;
  const short* qbase = q + (((size_t)(b * 16 + n)) << 18) + (size_t)(qt0 + w * 16) * 128;
  bf16x8 qa[4];
#pragma unroll
  for (int c = 0; c < 4; c++)
    qa[c] = *reinterpret_cast<const bf16x8*>(qbase + lr * 128 + c * 32 + lu * 8);
  f32x4 o[8] = {};
  float lsum = 0.f;
  const short* kbase = kk + (((size_t)(b * 4 + kv)) << 18);
  const short* vbase = vT + (((size_t)(b * 4 + kv)) << 18);
  char* lPw = (char*)lP[w];
  const int tw = qt0 + w * 16;
  const int t_row = tw + lu * 4;
  int st0 = qt0 - 1023; if (st0 < 0) st0 = 0;
  st0 >>= 6;
  const int stE = (qt0 + 127) >> 6;
  for (int st = st0; st <= stE; st++) {
    const int s0 = st << 6;
#pragma unroll
    for (int c = 0; c < 2; c++) {
      const int L = c * 8192 + tid * 16;
      {  // K tile: linear LDS dest, pre-swizzled global source
        const int s = L >> 8, slot = (L >> 4) & 15;
        const int sp = slot ^ (s & 7);
        __builtin_amdgcn_global_load_lds(
            (const __attribute__((address_space(1))) void*)(kbase + (size_t)(s0 + s) * 128 + sp * 8),
            (__attribute__((address_space(3))) void*)((char*)lK + L), 16, 0, 0);
      }
      {  // V tile
        const int h = L >> 7, slot = (L >> 4) & 7;
        const int u = slot ^ (h & 7);
        __builtin_amdgcn_global_load_lds(
            (const __attribute__((address_space(1))) void*)(vbase + (size_t)h * 2048 + s0 + u * 8),
            (__attribute__((address_space(3))) void*)((char*)lV + L), 16, 0, 0);
      }
    }
    __syncthreads();
    // ---- QK^T (swapped) ----
    f32x4 sc[4];
    __builtin_amdgcn_s_setprio(1);
#pragma unroll
    for (int cg = 0; cg < 4; cg++) {
      sc[cg] = (f32x4){0.f, 0.f, 0.f, 0.f};
      const int s = cg * 16 + lr;
      const int sw = (s & 7) << 4;
#pragma unroll
      for (int c = 0; c < 4; c++) {
        bf16x8 kb = *reinterpret_cast<const bf16x8*>((char*)lK + s * 256 + (((c * 4 + lu) << 4) ^ sw));
        sc[cg] = __builtin_amdgcn_mfma_f32_16x16x32_bf16(kb, qa[c], sc[cg], 0, 0, 0);
      }
    }
    __builtin_amdgcn_s_setprio(0);
    // ---- cubic soft-cap + exp, pack pairs, write P (b32) ----
    const bool allv = (s0 + 63 <= tw) && (s0 + 1008 >= tw);
    if (allv) {
#pragma unroll
      for (int cg = 0; cg < 4; cg++) {
        float pr[4];
#pragma unroll
        for (int r = 0; r < 4; r++) {
          const float x = sc[cg][r];
          const float cap = __builtin_fmaf(x * x * x, -1.3333333e-4f, x);
          const float p = __expf(cap);
          lsum += p;
          pr[r] = p;
        }
        unsigned w0, w1;
        asm("v_cvt_pk_bf16_f32 %0, %1, %2" : "=v"(w0) : "v"(pr[0]), "v"(pr[1]));
        asm("v_cvt_pk_bf16_f32 %0, %1, %2" : "=v"(w1) : "v"(pr[2]), "v"(pr[3]));
        const int sb = (cg * 16 + lu * 4) << 1;
        *(unsigned*)(lPw + (lr << 7) + (sb ^ ((lr & 7) << 4))) = w0;
        *(unsigned*)(lPw + (lr << 7) + ((sb + 4) ^ ((lr & 7) << 4))) = w1;
      }
    } else {
      const int t = tw + lr;
#pragma unroll
      for (int cg = 0; cg < 4; cg++) {
        float pr[4];
#pragma unroll
        for (int r = 0; r < 4; r++) {
          const int s = s0 + cg * 16 + lu * 4 + r;
          const bool valid = (s <= t) & (s + 1024 > t);
          const float x = sc[cg][r];
          const float cap = __builtin_fmaf(x * x * x, -1.3333333e-4f, x);
          float p = __expf(cap);
          p = valid ? p : 0.f;
          lsum += p;
          pr[r] = p;
        }
        unsigned w0, w1;
        asm("v_cvt_pk_bf16_f32 %0, %1, %2" : "=v"(w0) : "v"(pr[0]), "v"(pr[1]));
        asm("v_cvt_pk_bf16_f32 %0, %1, %2" : "=v"(w1) : "v"(pr[2]), "v"(pr[3]));
        const int sb = (cg * 16 + lu * 4) << 1;
        *(unsigned*)(lPw + (lr << 7) + (sb ^ ((lr & 7) << 4))) = w0;
        *(unsigned*)(lPw + (lr << 7) + ((sb + 4) ^ ((lr & 7) << 4))) = w1;
      }
    }
    // ---- PV ----
#pragma unroll
    for (int ks = 0; ks < 2; ks++) {
      const bf16x8 pf = *reinterpret_cast<const bf16x8*>(
          lPw + (lr << 7) + ((ks * 64 + lu * 16) ^ ((lr & 7) << 4)));
      __builtin_amdgcn_s_setprio(1);
#pragma unroll
      for (int oc = 0; oc < 8; oc++) {
        const int h = oc * 16 + lr;
        bf16x8 vb = *reinterpret_cast<const bf16x8*>(
            (char*)lV + h * 128 + (((ks * 4 + lu) << 4) ^ ((h & 7) << 4)));
        o[oc] = __builtin_amdgcn_mfma_f32_16x16x32_bf16(pf, vb, o[oc], 0, 0, 0);
      }
      __builtin_amdgcn_s_setprio(0);
    }
    __syncthreads();
  }
  // ---- reduce: lane holds partial sum for column t=tw+lr ----
  float tot = lsum;
  tot += __shfl_xor(tot, 16, 64);
  tot += __shfl_xor(tot, 32, 64);
  float rs[4];
#pragma unroll
  for (int r = 0; r < 4; r++)
    rs[r] = 1.f / __shfl(tot, lu * 4 + r, 64);
#pragma unroll
  for (int oc = 0; oc < 8; oc++)
#pragma unroll
    for (int r = 0; r < 4; r++) {
      const int t = t_row + r;
      enc[((size_t)b * 2048 + t) * 2048 + n * 128 + oc * 16 + lr] = f2bf(o[oc][r] * rs[r]);
    }
}

extern "C" void kernel_launch(void* const* d_in, const int* in_sizes, int n_in,
                              void* d_out, int out_size, void* d_ws, size_t ws_size,
                              hipStream_t stream) {
  (void)in_sizes; (void)n_in; (void)out_size; (void)ws_size;
  const float* x    = (const float*)d_in[0];
  const float* wq   = (const float*)d_in[3];
  const float* wkv  = (const float*)d_in[4];
  const float* wvec = (const float*)d_in[5];
  char* ws = (char*)d_ws;
  size_t off = 0;
  short* xbf   = (short*)(ws + off); off += (size_t)8388608 * 2;            // x bf16 [B*T][D]
  short* wall  = (short*)(ws + off); off += (size_t)3072 * 2048 * 2;        // [wqT|wkT|wvT] rows x K
  short* wvecT = (short*)(ws + off); off += (size_t)2048 * 2048 * 2;        // [d][nh]
  short* qbuf  = (short*)(ws + off); off += (size_t)2 * 16 * 2048 * 128 * 2; // q bf16 [b][n][t][h]
  short* kbuf  = (short*)(ws + off); off += (size_t)2 * 4 * 2048 * 128 * 2;  // k bf16 [b][kv][t][h]
  short* vTbuf = (short*)(ws + off); off += (size_t)2 * 4 * 128 * 2048 * 2;  // v^T [b][kv][h][s]
  short* encb  = (short*)(ws + off); off += (size_t)2 * 2048 * 2048 * 2;     // [b][t][nh]

  hipFuncSetAttribute(reinterpret_cast<const void*>(&k_gemm256<128, 384>),
                      hipFuncAttributeMaxDynamicSharedMemorySize, 131072);
  hipFuncSetAttribute(reinterpret_cast<const void*>(&k_gemm256<128, 256>),
                      hipFuncAttributeMaxDynamicSharedMemorySize, 98304);

  k_prep<<<18432, 256, 0, stream>>>(x, wq, wkv, wvec, xbf, wall, wvecT);
  k_gemm256<128, 384><<<dim3(32, 8), 512, 131072, stream>>>(xbf, wall, qbuf, kbuf, vTbuf,
                                                            3072, 2048, 0);
  k_attn<<<dim3(32, 16), 512, 0, stream>>>(qbuf, kbuf, vTbuf, encb);
  k_gemm256<128, 256><<<dim3(32, 8), 512, 98304, stream>>>(encb, wvecT, d_out, nullptr, nullptr,
                                                           2048, 2048, 2);
}